// Round 5
// baseline (313.174 us; speedup 1.0000x reference)
//
#include <hip/hip_runtime.h>
#include <math.h>

#define B_ 64
#define N_ 512
#define R_ (B_*N_)                  // 32768 rows
#define INV_S 0.9995003746877732f   // 1/sqrt(1+1e-3)

__device__ __forceinline__ float fast_tanh(float y){
  return 1.f - 2.f*__builtin_amdgcn_rcpf(1.f + __expf(2.f*y));
}
__device__ __forceinline__ float fast_sigmoid(float v){
  return __builtin_amdgcn_rcpf(1.f + __expf(-v));
}

struct GnnArgs {
  const float* xx;
  const float* emb1; const float* emb2; const float* emb3;
  const float* A0;  const float* b0;
  const float* Ar;  const float* br;
  const float* bng; const float* bnb;
  float4* cb0; float4* cb1;          // coords double-buffer (global)
  unsigned int* bar;                 // per-b barrier counters (64 x stride 32)
  float* xfinal;                     // final x for dense0 (R_ x 64)
};

// ---------------------------------------------------------------------------
// Scalar-A GEMM: wave w owns output cols [w*8, w*8+8) of BOTH matrices,
// lane = row. A addresses are wave-uniform (cw from readfirstlane) -> the
// compiler emits s_load; the fma is v_fmac vacc, sA, vx. x comes from the
// TRANSPOSED LDS tile xt[feat][row]: one conflict-free ds_read_b32 per k
// (lane-consecutive), reused for all 16 columns. K ascending per acc ->
// bit-identical to the previous float4 GEMM.
// ---------------------------------------------------------------------------
template<int K>
__device__ __forceinline__ void gemm_sw(const float* __restrict__ A, int cw,
                                        const float* __restrict__ xt, int lane,
                                        float acc1[8], float acc2[8])
{
  const float* Alo = A + cw;
  const float* Ahi = A + (size_t)K*64 + cw;
#pragma unroll
  for (int c=0;c<8;c++){ acc1[c]=0.f; acc2[c]=0.f; }
#pragma unroll 4
  for (int k=0;k<K;k++){
    float xv = xt[k*64 + lane];
#pragma unroll
    for (int c=0;c<8;c++) acc1[c] = fmaf(xv, Alo[k*64 + c], acc1[c]);
#pragma unroll
    for (int c=0;c<8;c++) acc2[c] = fmaf(xv, Ahi[k*64 + c], acc2[c]);
  }
}

// ---------------------------------------------------------------------------
// 5 fused GNN layers, plain launch, round-2 phase skeleton (no wave
// specialization). Per layer:
//   [k>=1] sync -> publish -> GEMM (block-local; hides barrier skew)
//          -> spin(tid0) -> sync -> cl stage -> sync
//   [k==0] build xt/cl/ml -> sync -> GEMM
//   S/T -> sync -> reduce(tid<64) -> sync -> epilogue (writes xt in place)
// LDS ~28.5 KB (A never staged: scalar-pipe reads), so co-residency of the
// 512-block grid has 2x slack (wave-slot cap 4 blocks/CU, 1024 slots).
// grid (64,8): all 8 blocks of one b on the same XCD (L2-local cb+barrier).
// All accumulation orders preserved -> bitwise-identical output.
// ---------------------------------------------------------------------------
__global__ __launch_bounds__(512, 4) void gnn_fused(GnnArgs g)
{
  __shared__ float xt[64*64];           // 16 KB, x^T: [feat][row]
  __shared__ float4 cl[512];            // 8 KB: coords of all 512 rows of b
  __shared__ float spart[512], tpart[512];
  __shared__ float scl[64], tcl[64], ml[64];

  const int tid   = threadIdx.x;
  const int lane  = tid & 63;
  const int w     = __builtin_amdgcn_readfirstlane(tid >> 6);  // wave id 0..7
  const int cw    = w*8;                 // this wave's output-col base
  const int b     = blockIdx.x;          // 0..63
  const int jc    = blockIdx.y;          // 0..7
  const int jloc  = jc*64;
  const int rbase = b*N_;
  unsigned int* barp = g.bar + b*32;     // 128B-strided counters

  for (int k = 0; k < 5; ++k){
    const float* A;  const float* bi;  int K;
    if (k == 0){ A = g.A0;                        bi = g.b0;            K = 33; }
    else       { A = g.Ar + (size_t)(k-1)*129*64; bi = g.br + (k-1)*64; K = 64; }
    const float* gam = g.bng + k*64;
    const float* bet = g.bnb + k*64;

    if (k == 0){
      // ---- build transposed x0 tile + cl + mask ----
      {
        const float* xr = g.xx + (size_t)(rbase + tid)*30;
        cl[tid] = make_float4(xr[25], xr[26], 0.f, 0.f);
      }
      if (tid < 64){
        const float* row = g.xx + (size_t)(rbase + jloc + tid)*30;
        float v[30];
#pragma unroll
        for (int i=0;i<30;i++) v[i] = row[i];
        int i1 = (int)fabsf(v[27]);
        int i2 = (int)fabsf(v[28]);
        int i3 = (int)fabsf(v[29]);
        xt[0*64+tid] = g.emb1[i1*2+0];
        xt[1*64+tid] = g.emb1[i1*2+1];
        xt[2*64+tid] = g.emb2[i2*2+0];
        xt[3*64+tid] = g.emb2[i2*2+1];
        xt[4*64+tid] = g.emb3[i3*2+0];
        xt[5*64+tid] = g.emb3[i3*2+1];
#pragma unroll
        for (int i=0;i<27;i++) xt[(6+i)*64 + tid] = v[i];
        ml[tid] = v[0];
      }
      __syncthreads();                 // xt/cl/ml ready
    } else {
      __syncthreads();                 // SYNC_PRE: prev epilogue + cb drained
      if (tid == 0){
        __builtin_amdgcn_fence(__ATOMIC_RELEASE, "agent");
        __hip_atomic_fetch_add(barp, 1u, __ATOMIC_RELAXED, __HIP_MEMORY_SCOPE_AGENT);
      }
    }

    // ---- GEMM: block-local (xt + scalar A), no barrier dependency ----
    float acc1[8], acc2[8];
    if (k == 0) gemm_sw<33>(A, cw, xt, lane, acc1, acc2);
    else        gemm_sw<64>(A, cw, xt, lane, acc1, acc2);

    // ---- inter-block coords barrier (skew hidden by the GEMM above) ----
    if (k >= 1){
      if (tid == 0){
        unsigned int tgt = 8u*(unsigned int)k;
        while (__hip_atomic_load(barp, __ATOMIC_RELAXED, __HIP_MEMORY_SCOPE_AGENT) < tgt)
          __builtin_amdgcn_s_sleep(2);
        __builtin_amdgcn_fence(__ATOMIC_ACQUIRE, "agent");
      }
      __syncthreads();                 // all 8 blocks' coords visible
      const float4* cbr = ((k & 1) ? g.cb0 : g.cb1) + rbase;
      cl[tid] = cbr[tid];              // coalesced stage of all 512 coords
      __syncthreads();                 // cl ready
    }

    // ---- S/T partials: jj = tid&63 (row), ic = tid>>6 (64-i chunk).
    //      cl reads wave-uniform -> LDS broadcast, conflict-free. ----
    {
      int jj = tid & 63, ic = tid >> 6, base = ic*64;
      float Ss = 0.f, Ts = 0.f;
      if (k == 0){                      // 2-component (z=w=0 exactly)
        const float* xj = g.xx + (size_t)(rbase + jloc + jj)*30;
        float cjx = xj[25], cjy = xj[26];
#pragma unroll 8
        for (int i=0;i<64;i++){
          float4 ci = cl[base+i];
          float d0 = cjx-ci.x, d1 = cjy-ci.y;
          float dist = d0*d0 + d1*d1;
          float wgt = __expf(-10.f*dist);
          Ss += wgt; Ts += dist*wgt;
        }
      } else {
        float4 cj = make_float4(xt[60*64+jj], xt[61*64+jj],
                                xt[62*64+jj], xt[63*64+jj]);
#pragma unroll 8
        for (int i=0;i<64;i++){
          float4 ci = cl[base+i];
          float d0 = cj.x-ci.x, d1 = cj.y-ci.y, d2 = cj.z-ci.z, d3 = cj.w-ci.w;
          float dist = d0*d0 + d1*d1 + d2*d2 + d3*d3;
          float wgt = __expf(-10.f*dist);
          Ss += wgt; Ts += dist*wgt;
        }
      }
      spart[tid] = Ss;
      tpart[tid] = Ts;
    }
    __syncthreads();                   // spart/tpart ready (GEMM reads done too)

    if (tid < 64){
      float S = 0.f, T = 0.f;
#pragma unroll
      for (int c=0;c<8;c++){
        S += spart[tid + 64*c];
        T += tpart[tid + 64*c];
      }
      float m = ml[tid];
      scl[tid] = m*S - 1.f;
      tcl[tid] = m*T;
    }
    __syncthreads();                   // scl/tcl ready

    // ---- epilogue: lane = row, cols cw..cw+7; writes xt in place ----
    {
      float m  = ml[lane];
      float sc = scl[lane];
      float tc = tcl[lane];
      float t[8];
#pragma unroll
      for (int c=0;c<8;c++){
        float alast = A[(size_t)2*K*64 + cw + c];   // scalar (uniform)
        float boc = bi[cw + c];
        float goc = gam[cw + c];
        float bbc = bet[cw + c];
        float v = (acc1[c] + sc*acc2[c] + tc*alast + boc)*m;
        t[c] = fast_tanh(goc*(v*INV_S) + bbc);
        xt[(cw+c)*64 + lane] = t[c];               // in place: reads done
      }
      if (k < 4 && w == 7){                        // cols 60..63 = coords
        float4* cbw = (k & 1) ? g.cb1 : g.cb0;
        cbw[rbase + jloc + lane] = make_float4(t[4], t[5], t[6], t[7]);
      }
    }
  }

  // ---- write-out: transpose xt back to row-major xfinal (coalesced) ----
  __syncthreads();
  for (int idx = tid; idx < 1024; idx += 512){
    int row = idx >> 4, q = idx & 15;
    float4 v = make_float4(xt[(q*4+0)*64 + row], xt[(q*4+1)*64 + row],
                           xt[(q*4+2)*64 + row], xt[(q*4+3)*64 + row]);
    *(float4*)&g.xfinal[(size_t)(rbase + jloc + row)*64 + q*4] = v;
  }
}

// ---------------------------------------------------------------------------
// dense0 split-K partials (unchanged).
// ---------------------------------------------------------------------------
__global__ __launch_bounds__(256) void dense0_partial(
    const float* __restrict__ X, const float* __restrict__ W,
    float* __restrict__ partial)
{
  __shared__ float xt[64*32];
  __shared__ float wt[32*128];
  int tid = threadIdx.x;
  int k0 = blockIdx.x*128;
  int og = (tid & 15)*8;
  int rg = (tid >> 4)*4;
  float acc[4][8];
#pragma unroll
  for (int a=0;a<4;a++)
#pragma unroll
    for (int u=0;u<8;u++) acc[a][u]=0.f;
  for (int kt = 0; kt < 128; kt += 32){
    __syncthreads();
    for (int idx = tid; idx < 512; idx += 256){
      int r = idx >> 3, kq = idx & 7;
      *(float4*)&xt[r*32 + kq*4] =
          *(const float4*)&X[(size_t)r*32768 + k0 + kt + kq*4];
    }
    {
      const float4* Wc = (const float4*)&W[(size_t)(k0+kt)*128];
      float4* wt4 = (float4*)wt;
      for (int idx = tid; idx < 1024; idx += 256) wt4[idx] = Wc[idx];
    }
    __syncthreads();
#pragma unroll 4
    for (int k=0;k<32;k++){
      float4 w0 = *(const float4*)&wt[k*128 + og];
      float4 w1 = *(const float4*)&wt[k*128 + og + 4];
      float xv[4];
#pragma unroll
      for (int rr=0;rr<4;rr++) xv[rr] = xt[(rg+rr)*32 + k];
#pragma unroll
      for (int rr=0;rr<4;rr++){
        acc[rr][0] = fmaf(xv[rr], w0.x, acc[rr][0]);
        acc[rr][1] = fmaf(xv[rr], w0.y, acc[rr][1]);
        acc[rr][2] = fmaf(xv[rr], w0.z, acc[rr][2]);
        acc[rr][3] = fmaf(xv[rr], w0.w, acc[rr][3]);
        acc[rr][4] = fmaf(xv[rr], w1.x, acc[rr][4]);
        acc[rr][5] = fmaf(xv[rr], w1.y, acc[rr][5]);
        acc[rr][6] = fmaf(xv[rr], w1.z, acc[rr][6]);
        acc[rr][7] = fmaf(xv[rr], w1.w, acc[rr][7]);
      }
    }
  }
  float* pb = partial + (size_t)blockIdx.x*8192;
#pragma unroll
  for (int rr=0;rr<4;rr++){
    *(float4*)&pb[(rg+rr)*128 + og]     = *(float4*)&acc[rr][0];
    *(float4*)&pb[(rg+rr)*128 + og + 4] = *(float4*)&acc[rr][4];
  }
}

// ---------------------------------------------------------------------------
// Head (unchanged).
// ---------------------------------------------------------------------------
__global__ __launch_bounds__(256) void dense_head(
    const float* __restrict__ partial,
    const float* __restrict__ db0, const float* __restrict__ dg0,
    const float* __restrict__ dbb0,
    const float* __restrict__ dW1, const float* __restrict__ db1,
    const float* __restrict__ dg1, const float* __restrict__ dbb1,
    const float* __restrict__ W2, const float* __restrict__ b2,
    float* __restrict__ out)
{
  __shared__ float sred[256];
  __shared__ float h[128];
  __shared__ float red0[128], red1[128];
  int tid = threadIdx.x;
  int b = blockIdx.x;
  int o = tid & 127, ph = tid >> 7;
  float s = 0.f;
#pragma unroll 16
  for (int p = ph*128; p < ph*128+128; p++)
    s += partial[(size_t)p*8192 + b*128 + o];
  sred[tid] = s;
  __syncthreads();
  if (tid < 128){
    float sum = sred[tid] + sred[tid+128];
    float v = dg0[tid]*((sum + db0[tid])*INV_S) + dbb0[tid];
    h[tid] = fast_sigmoid(v);
  }
  __syncthreads();
  if (tid < 128){
    float acc = 0.f;
#pragma unroll 8
    for (int k=0;k<128;k++) acc = fmaf(h[k], dW1[k*128 + tid], acc);
    float v = dg1[tid]*((acc + db1[tid])*INV_S) + dbb1[tid];
    float h1 = fast_sigmoid(v);
    red0[tid] = h1 * W2[tid*2+0];
    red1[tid] = h1 * W2[tid*2+1];
  }
  __syncthreads();
  for (int st=64; st>0; st>>=1){
    if (tid < st){ red0[tid] += red0[tid+st]; red1[tid] += red1[tid+st]; }
    __syncthreads();
  }
  if (tid == 0){
    out[b*4+0] = red0[0] + b2[0];
    out[b*4+1] = red1[0] + b2[1];
    out[b*4+2] = 0.f;
    out[b*4+3] = 0.f;
  }
}

// ---------------------------------------------------------------------------
extern "C" void kernel_launch(void* const* d_in, const int* in_sizes, int n_in,
                              void* d_out, int out_size, void* d_ws, size_t ws_size,
                              hipStream_t stream)
{
  const float* xx   = (const float*)d_in[0];
  const float* emb1 = (const float*)d_in[1];
  const float* emb2 = (const float*)d_in[2];
  const float* emb3 = (const float*)d_in[3];
  const float* A0   = (const float*)d_in[4];
  const float* b0   = (const float*)d_in[5];
  const float* Ar   = (const float*)d_in[6];   // (4,129,64)
  const float* br   = (const float*)d_in[7];   // (4,64)
  const float* bng  = (const float*)d_in[8];   // (5,64)
  const float* bnb  = (const float*)d_in[9];   // (5,64)
  const float* dW0  = (const float*)d_in[10];  // (32768,128)
  const float* db0  = (const float*)d_in[11];
  const float* dW1  = (const float*)d_in[12];  // (128,128)
  const float* db1  = (const float*)d_in[13];
  const float* dbg  = (const float*)d_in[14];  // (2,128)
  const float* dbb  = (const float*)d_in[15];
  const float* W2   = (const float*)d_in[16];  // (128,2)
  const float* b2   = (const float*)d_in[17];

  float* ws = (float*)d_ws;
  float*  xA      = ws;                               // 32768*64
  float*  partial = xA + (size_t)R_*64;               // 256*8192
  float4* cb0     = (float4*)(partial + (size_t)256*8192);  // 32768 float4
  float4* cb1     = cb0 + R_;                         // 32768 float4
  unsigned int* bar = (unsigned int*)(cb1 + R_);      // 64*32 uints

  // barrier counters must start at 0 (workspace is poisoned, not zeroed)
  hipMemsetAsync(bar, 0, 64*32*sizeof(unsigned int), stream);

  GnnArgs ga;
  ga.xx = xx; ga.emb1 = emb1; ga.emb2 = emb2; ga.emb3 = emb3;
  ga.A0 = A0; ga.b0 = b0; ga.Ar = Ar; ga.br = br;
  ga.bng = bng; ga.bnb = bnb;
  ga.cb0 = cb0; ga.cb1 = cb1; ga.bar = bar; ga.xfinal = xA;

  // Plain launch. LDS ~28.5 KB + 8 waves/block -> wave-slot-capped at
  // 4 blocks/CU = 1024 slots >= 512 blocks: all co-resident (2x slack).
  hipLaunchKernelGGL(gnn_fused, dim3(64,8), dim3(512), 0, stream, ga);

  dense0_partial<<<256, 256, 0, stream>>>(xA, dW0, partial);
  dense_head<<<B_, 256, 0, stream>>>(partial, db0, dbg, dbb,
                                     dW1, db1, dbg + 128, dbb + 128,
                                     W2, b2, (float*)d_out);
}

// Round 6
// 232.975 us; speedup vs baseline: 1.3442x; 1.3442x over previous
//
#include <hip/hip_runtime.h>
#include <math.h>

#define B_ 64
#define N_ 512
#define R_ (B_*N_)                  // 32768 rows
#define INV_S 0.9995003746877732f   // 1/sqrt(1+1e-3)

#define CONST_AS __attribute__((address_space(4)))
typedef float f8v __attribute__((ext_vector_type(8)));

__device__ __forceinline__ const CONST_AS float* cptr(const float* p){
  return (const CONST_AS float*)(unsigned long long)p;   // inttoptr -> AS4
}

__device__ __forceinline__ float fast_tanh(float y){
  return 1.f - 2.f*__builtin_amdgcn_rcpf(1.f + __expf(2.f*y));
}
__device__ __forceinline__ float fast_sigmoid(float v){
  return __builtin_amdgcn_rcpf(1.f + __expf(-v));
}

struct GnnArgs {
  const float* xx;
  const float* emb1; const float* emb2; const float* emb3;
  const float* A0;  const float* b0;
  const float* Ar;  const float* br;
  const float* bng; const float* bnb;
  float4* cb0; float4* cb1;          // coords double-buffer (global)
  unsigned int* bar;                 // per-b barrier counters (64 x stride 32)
  float* xfinal;                     // final x for dense0 (R_ x 64)
};

// ---------------------------------------------------------------------------
// Scalar-A GEMM: wave w owns output cols [w*8,w*8+8) of BOTH matrices,
// lane = row. A is cast to constant address space (AS4): invariant +
// wave-uniform address (cw from readfirstlane, k uniform) -> the compiler
// emits s_load_dwordx8 on the SMEM pipe; fma is v_fmac vacc, sA, vx.
// x: one conflict-free ds_read_b32 per k from the transposed tile
// xt[feat][row] (lane-consecutive). K ascending per accumulator ->
// bit-identical to all previous versions.
// ---------------------------------------------------------------------------
template<int K>
__device__ __forceinline__ void gemm_sw(const float* A, int cw,
                                        const float* xt, int lane,
                                        float acc1[8], float acc2[8])
{
  const CONST_AS float* Alo = cptr(A) + cw;
  const CONST_AS float* Ahi = Alo + (size_t)K*64;
#pragma unroll
  for (int c=0;c<8;c++){ acc1[c]=0.f; acc2[c]=0.f; }
#pragma unroll 4
  for (int k=0;k<K;k++){
    f8v a1 = *(const CONST_AS f8v*)(Alo + k*64);   // s_load_dwordx8
    f8v a2 = *(const CONST_AS f8v*)(Ahi + k*64);   // s_load_dwordx8
    float xv = xt[k*64 + lane];                    // ds_read_b32, 2/bank
#pragma unroll
    for (int c=0;c<8;c++) acc1[c] = fmaf(xv, a1[c], acc1[c]);
#pragma unroll
    for (int c=0;c<8;c++) acc2[c] = fmaf(xv, a2[c], acc2[c]);
  }
}

// ---------------------------------------------------------------------------
// 5 fused GNN layers, plain launch. Per layer:
//   [k==0] build xt/cl/ml -> sync
//   [k>=1] sync (SYNC_PRE) -> publish
//   GEMM (block-local: xt + scalar A; hides barrier skew + smem latency)
//   [k>=1] spin(tid0) -> sync -> cl stage -> sync
//   S/T -> sync -> reduce(tid<64) -> sync -> epilogue (writes xt in place)
// LDS ~29.5 KB; capacity 256 CU x 4 blocks (wave cap) = 1024 slots >= 512
// blocks -> all co-resident regardless of packing -> barrier deadlock-free.
// grid (64,8): all 8 blocks of one b on the same XCD (L2-local cb+barrier).
// All accumulation orders preserved -> bitwise-identical output.
// ---------------------------------------------------------------------------
__global__ __launch_bounds__(512, 4) void gnn_fused(GnnArgs g)
{
  __shared__ float xt[64*64];           // 16 KB, x^T: [feat][row]
  __shared__ float4 cl[512];            // 8 KB: coords of all 512 rows of b
  __shared__ float spart[512], tpart[512];
  __shared__ float scl[64], tcl[64], ml[64];

  const int tid   = threadIdx.x;
  const int lane  = tid & 63;
  const int w     = __builtin_amdgcn_readfirstlane(tid >> 6);  // wave id 0..7
  const int cw    = w*8;                 // this wave's output-col base
  const int b     = blockIdx.x;          // 0..63
  const int jc    = blockIdx.y;          // 0..7
  const int jloc  = jc*64;
  const int rbase = b*N_;
  unsigned int* barp = g.bar + b*32;     // 128B-strided counters

  for (int k = 0; k < 5; ++k){
    const float* A;  const float* bi;  int K;
    if (k == 0){ A = g.A0;                        bi = g.b0;            K = 33; }
    else       { A = g.Ar + (size_t)(k-1)*129*64; bi = g.br + (k-1)*64; K = 64; }
    const float* gam = g.bng + k*64;
    const float* bet = g.bnb + k*64;

    if (k == 0){
      // ---- build transposed x0 tile + cl + mask ----
      {
        const float* xr = g.xx + (size_t)(rbase + tid)*30;
        cl[tid] = make_float4(xr[25], xr[26], 0.f, 0.f);
      }
      if (tid < 64){
        const float* row = g.xx + (size_t)(rbase + jloc + tid)*30;
        float v[30];
#pragma unroll
        for (int i=0;i<30;i++) v[i] = row[i];
        int i1 = (int)fabsf(v[27]);
        int i2 = (int)fabsf(v[28]);
        int i3 = (int)fabsf(v[29]);
        xt[0*64+tid] = g.emb1[i1*2+0];
        xt[1*64+tid] = g.emb1[i1*2+1];
        xt[2*64+tid] = g.emb2[i2*2+0];
        xt[3*64+tid] = g.emb2[i2*2+1];
        xt[4*64+tid] = g.emb3[i3*2+0];
        xt[5*64+tid] = g.emb3[i3*2+1];
#pragma unroll
        for (int i=0;i<27;i++) xt[(6+i)*64 + tid] = v[i];
        ml[tid] = v[0];
      }
      __syncthreads();                 // xt/cl/ml ready
    } else {
      __syncthreads();                 // SYNC_PRE: prev epilogue + cb drained
      if (tid == 0){
        __builtin_amdgcn_fence(__ATOMIC_RELEASE, "agent");
        __hip_atomic_fetch_add(barp, 1u, __ATOMIC_RELAXED, __HIP_MEMORY_SCOPE_AGENT);
      }
    }

    // ---- GEMM: block-local (xt + scalar A), no barrier dependency ----
    float acc1[8], acc2[8];
    if (k == 0) gemm_sw<33>(A, cw, xt, lane, acc1, acc2);
    else        gemm_sw<64>(A, cw, xt, lane, acc1, acc2);

    // ---- inter-block coords barrier (skew hidden by the GEMM above) ----
    if (k >= 1){
      if (tid == 0){
        unsigned int tgt = 8u*(unsigned int)k;
        while (__hip_atomic_load(barp, __ATOMIC_RELAXED, __HIP_MEMORY_SCOPE_AGENT) < tgt)
          __builtin_amdgcn_s_sleep(2);
        __builtin_amdgcn_fence(__ATOMIC_ACQUIRE, "agent");
      }
      __syncthreads();                 // all 8 blocks' coords visible
      const float4* cbr = ((k & 1) ? g.cb0 : g.cb1) + rbase;
      cl[tid] = cbr[tid];              // coalesced stage of all 512 coords
      __syncthreads();                 // cl ready
    }

    // ---- S/T partials: jj = tid&63 (row), ic = tid>>6 (64-i chunk).
    //      cl reads wave-uniform -> LDS broadcast, conflict-free. ----
    {
      int jj = tid & 63, ic = tid >> 6, base = ic*64;
      float Ss = 0.f, Ts = 0.f;
      if (k == 0){                      // 2-component (z=w=0 exactly)
        const float* xj = g.xx + (size_t)(rbase + jloc + jj)*30;
        float cjx = xj[25], cjy = xj[26];
#pragma unroll 8
        for (int i=0;i<64;i++){
          float4 ci = cl[base+i];
          float d0 = cjx-ci.x, d1 = cjy-ci.y;
          float dist = d0*d0 + d1*d1;
          float wgt = __expf(-10.f*dist);
          Ss += wgt; Ts += dist*wgt;
        }
      } else {
        float4 cj = make_float4(xt[60*64+jj], xt[61*64+jj],
                                xt[62*64+jj], xt[63*64+jj]);
#pragma unroll 8
        for (int i=0;i<64;i++){
          float4 ci = cl[base+i];
          float d0 = cj.x-ci.x, d1 = cj.y-ci.y, d2 = cj.z-ci.z, d3 = cj.w-ci.w;
          float dist = d0*d0 + d1*d1 + d2*d2 + d3*d3;
          float wgt = __expf(-10.f*dist);
          Ss += wgt; Ts += dist*wgt;
        }
      }
      spart[tid] = Ss;
      tpart[tid] = Ts;
    }
    __syncthreads();                   // spart/tpart ready (GEMM reads done too)

    if (tid < 64){
      float S = 0.f, T = 0.f;
#pragma unroll
      for (int c=0;c<8;c++){
        S += spart[tid + 64*c];
        T += tpart[tid + 64*c];
      }
      float m = ml[tid];
      scl[tid] = m*S - 1.f;
      tcl[tid] = m*T;
    }
    __syncthreads();                   // scl/tcl ready

    // ---- epilogue: lane = row, cols cw..cw+7; writes xt in place ----
    {
      const CONST_AS float* Ac  = cptr(A);
      const CONST_AS float* bic = cptr(bi);
      const CONST_AS float* gac = cptr(gam);
      const CONST_AS float* bec = cptr(bet);
      float m  = ml[lane];
      float sc = scl[lane];
      float tc = tcl[lane];
      float t[8];
#pragma unroll
      for (int c=0;c<8;c++){
        float alast = Ac[(size_t)2*K*64 + cw + c];   // s_load (uniform)
        float boc = bic[cw + c];
        float goc = gac[cw + c];
        float bbc = bec[cw + c];
        float v = (acc1[c] + sc*acc2[c] + tc*alast + boc)*m;
        t[c] = fast_tanh(goc*(v*INV_S) + bbc);
        xt[(cw+c)*64 + lane] = t[c];               // in place: reads done
      }
      if (k < 4 && w == 7){                        // cols 60..63 = coords
        float4* cbw = (k & 1) ? g.cb1 : g.cb0;
        cbw[rbase + jloc + lane] = make_float4(t[4], t[5], t[6], t[7]);
      }
    }
  }

  // ---- write-out: transpose xt back to row-major xfinal (coalesced) ----
  __syncthreads();
  for (int idx = tid; idx < 1024; idx += 512){
    int row = idx >> 4, q = idx & 15;
    float4 v = make_float4(xt[(q*4+0)*64 + row], xt[(q*4+1)*64 + row],
                           xt[(q*4+2)*64 + row], xt[(q*4+3)*64 + row]);
    *(float4*)&g.xfinal[(size_t)(rbase + jloc + row)*64 + q*4] = v;
  }
}

// ---------------------------------------------------------------------------
// dense0 split-K partials (unchanged).
// ---------------------------------------------------------------------------
__global__ __launch_bounds__(256) void dense0_partial(
    const float* __restrict__ X, const float* __restrict__ W,
    float* __restrict__ partial)
{
  __shared__ float xt[64*32];
  __shared__ float wt[32*128];
  int tid = threadIdx.x;
  int k0 = blockIdx.x*128;
  int og = (tid & 15)*8;
  int rg = (tid >> 4)*4;
  float acc[4][8];
#pragma unroll
  for (int a=0;a<4;a++)
#pragma unroll
    for (int u=0;u<8;u++) acc[a][u]=0.f;
  for (int kt = 0; kt < 128; kt += 32){
    __syncthreads();
    for (int idx = tid; idx < 512; idx += 256){
      int r = idx >> 3, kq = idx & 7;
      *(float4*)&xt[r*32 + kq*4] =
          *(const float4*)&X[(size_t)r*32768 + k0 + kt + kq*4];
    }
    {
      const float4* Wc = (const float4*)&W[(size_t)(k0+kt)*128];
      float4* wt4 = (float4*)wt;
      for (int idx = tid; idx < 1024; idx += 256) wt4[idx] = Wc[idx];
    }
    __syncthreads();
#pragma unroll 4
    for (int k=0;k<32;k++){
      float4 w0 = *(const float4*)&wt[k*128 + og];
      float4 w1 = *(const float4*)&wt[k*128 + og + 4];
      float xv[4];
#pragma unroll
      for (int rr=0;rr<4;rr++) xv[rr] = xt[(rg+rr)*32 + k];
#pragma unroll
      for (int rr=0;rr<4;rr++){
        acc[rr][0] = fmaf(xv[rr], w0.x, acc[rr][0]);
        acc[rr][1] = fmaf(xv[rr], w0.y, acc[rr][1]);
        acc[rr][2] = fmaf(xv[rr], w0.z, acc[rr][2]);
        acc[rr][3] = fmaf(xv[rr], w0.w, acc[rr][3]);
        acc[rr][4] = fmaf(xv[rr], w1.x, acc[rr][4]);
        acc[rr][5] = fmaf(xv[rr], w1.y, acc[rr][5]);
        acc[rr][6] = fmaf(xv[rr], w1.z, acc[rr][6]);
        acc[rr][7] = fmaf(xv[rr], w1.w, acc[rr][7]);
      }
    }
  }
  float* pb = partial + (size_t)blockIdx.x*8192;
#pragma unroll
  for (int rr=0;rr<4;rr++){
    *(float4*)&pb[(rg+rr)*128 + og]     = *(float4*)&acc[rr][0];
    *(float4*)&pb[(rg+rr)*128 + og + 4] = *(float4*)&acc[rr][4];
  }
}

// ---------------------------------------------------------------------------
// Head (unchanged).
// ---------------------------------------------------------------------------
__global__ __launch_bounds__(256) void dense_head(
    const float* __restrict__ partial,
    const float* __restrict__ db0, const float* __restrict__ dg0,
    const float* __restrict__ dbb0,
    const float* __restrict__ dW1, const float* __restrict__ db1,
    const float* __restrict__ dg1, const float* __restrict__ dbb1,
    const float* __restrict__ W2, const float* __restrict__ b2,
    float* __restrict__ out)
{
  __shared__ float sred[256];
  __shared__ float h[128];
  __shared__ float red0[128], red1[128];
  int tid = threadIdx.x;
  int b = blockIdx.x;
  int o = tid & 127, ph = tid >> 7;
  float s = 0.f;
#pragma unroll 16
  for (int p = ph*128; p < ph*128+128; p++)
    s += partial[(size_t)p*8192 + b*128 + o];
  sred[tid] = s;
  __syncthreads();
  if (tid < 128){
    float sum = sred[tid] + sred[tid+128];
    float v = dg0[tid]*((sum + db0[tid])*INV_S) + dbb0[tid];
    h[tid] = fast_sigmoid(v);
  }
  __syncthreads();
  if (tid < 128){
    float acc = 0.f;
#pragma unroll 8
    for (int k=0;k<128;k++) acc = fmaf(h[k], dW1[k*128 + tid], acc);
    float v = dg1[tid]*((acc + db1[tid])*INV_S) + dbb1[tid];
    float h1 = fast_sigmoid(v);
    red0[tid] = h1 * W2[tid*2+0];
    red1[tid] = h1 * W2[tid*2+1];
  }
  __syncthreads();
  for (int st=64; st>0; st>>=1){
    if (tid < st){ red0[tid] += red0[tid+st]; red1[tid] += red1[tid+st]; }
    __syncthreads();
  }
  if (tid == 0){
    out[b*4+0] = red0[0] + b2[0];
    out[b*4+1] = red1[0] + b2[1];
    out[b*4+2] = 0.f;
    out[b*4+3] = 0.f;
  }
}

// ---------------------------------------------------------------------------
extern "C" void kernel_launch(void* const* d_in, const int* in_sizes, int n_in,
                              void* d_out, int out_size, void* d_ws, size_t ws_size,
                              hipStream_t stream)
{
  const float* xx   = (const float*)d_in[0];
  const float* emb1 = (const float*)d_in[1];
  const float* emb2 = (const float*)d_in[2];
  const float* emb3 = (const float*)d_in[3];
  const float* A0   = (const float*)d_in[4];
  const float* b0   = (const float*)d_in[5];
  const float* Ar   = (const float*)d_in[6];   // (4,129,64)
  const float* br   = (const float*)d_in[7];   // (4,64)
  const float* bng  = (const float*)d_in[8];   // (5,64)
  const float* bnb  = (const float*)d_in[9];   // (5,64)
  const float* dW0  = (const float*)d_in[10];  // (32768,128)
  const float* db0  = (const float*)d_in[11];
  const float* dW1  = (const float*)d_in[12];  // (128,128)
  const float* db1  = (const float*)d_in[13];
  const float* dbg  = (const float*)d_in[14];  // (2,128)
  const float* dbb  = (const float*)d_in[15];
  const float* W2   = (const float*)d_in[16];  // (128,2)
  const float* b2   = (const float*)d_in[17];

  float* ws = (float*)d_ws;
  float*  xA      = ws;                               // 32768*64
  float*  partial = xA + (size_t)R_*64;               // 256*8192
  float4* cb0     = (float4*)(partial + (size_t)256*8192);  // 32768 float4
  float4* cb1     = cb0 + R_;                         // 32768 float4
  unsigned int* bar = (unsigned int*)(cb1 + R_);      // 64*32 uints

  // barrier counters must start at 0 (workspace is poisoned, not zeroed)
  hipMemsetAsync(bar, 0, 64*32*sizeof(unsigned int), stream);

  GnnArgs ga;
  ga.xx = xx; ga.emb1 = emb1; ga.emb2 = emb2; ga.emb3 = emb3;
  ga.A0 = A0; ga.b0 = b0; ga.Ar = Ar; ga.br = br;
  ga.bng = bng; ga.bnb = bnb;
  ga.cb0 = cb0; ga.cb1 = cb1; ga.bar = bar; ga.xfinal = xA;

  // Plain launch. LDS ~29.5 KB + 8 waves/block -> wave-slot cap 4 blocks/CU
  // -> 1024 slots >= 512 blocks: all co-resident (2x slack).
  hipLaunchKernelGGL(gnn_fused, dim3(64,8), dim3(512), 0, stream, ga);

  dense0_partial<<<256, 256, 0, stream>>>(xA, dW0, partial);
  dense_head<<<B_, 256, 0, stream>>>(partial, db0, dbg, dbb,
                                     dW1, db1, dbg + 128, dbb + 128,
                                     W2, b2, (float*)d_out);
}